// Round 4
// baseline (53.404 us; speedup 1.0000x reference)
//
#include <hip/hip_runtime.h>
#include <math.h>

#define B 2048
#define D 512
#define NC 32
#define SLICES 32   // top2 pair-space splits per class (32 slices x 2 vals = 64 = 1 wave)

// ---------------------------------------------------------------------------
// Workspace layout:
//   float centers[NC][D]
//   float blk_top[NC][SLICES][2]
// ---------------------------------------------------------------------------

// Build this block's class member list in LDS via wave shuffle-scan.
// Thread t scans contiguous chunk [8t, 8t+8) so list order == index order.
__device__ inline int build_slist(const int* __restrict__ target, int c,
                                  int* slist, int* wtot) {
    const int t = threadIdx.x;
    const int wave = t >> 6;
    const int lane = t & 63;
    const int base = t * 8;

    int flags[8];
    int local = 0;
#pragma unroll
    for (int k = 0; k < 8; ++k) {
        flags[k] = (target[base + k] == c) ? 1 : 0;
        local += flags[k];
    }
    // inclusive scan across the 64-lane wave
    int incl = local;
#pragma unroll
    for (int off = 1; off < 64; off <<= 1) {
        const int v = __shfl_up(incl, off, 64);
        if (lane >= off) incl += v;
    }
    if (lane == 63) wtot[wave] = incl;
    __syncthreads();
    int wbase = 0;
    for (int w = 0; w < wave; ++w) wbase += wtot[w];
    const int n = wtot[0] + wtot[1] + wtot[2] + wtot[3];
    int pos = wbase + incl - local;  // exclusive prefix
#pragma unroll
    for (int k = 0; k < 8; ++k) {
        if (flags[k]) slist[pos++] = base + k;
    }
    __syncthreads();
    return n;
}

// Fused: blockIdx.y==0 -> per-class center; else top-2 pair-distance slice.
__global__ void fused_main_kernel(const float* __restrict__ y,
                                  const int* __restrict__ target,
                                  float* __restrict__ centers,
                                  float* __restrict__ blk_top) {
    const int c = blockIdx.x;
    const int t = threadIdx.x;
    const int wave = t >> 6;
    const int lane = t & 63;

    __shared__ int slist[B];
    __shared__ int wtot[4];
    const int n = build_slist(target, c, slist, wtot);

    if (blockIdx.y == 0) {
        // -------- centers role: thread owns dims t and t+256 --------
        float acc0 = 0.f, acc1 = 0.f;
        for (int m = 0; m < n; ++m) {
            const float* row = y + (size_t)slist[m] * D;
            acc0 += row[t];
            acc1 += row[t + 256];
        }
        const float den = fmaxf((float)n, 1.0f);
        centers[c * D + t]       = acc0 / den;
        centers[c * D + t + 256] = acc1 / den;
        return;
    }

    // -------- top2 role: one wave per pair slot, lanes split D --------
    const int s = blockIdx.y - 1;
    float t0 = -INFINITY, t1 = -INFINITY;
    const int nn = n * n;
    for (int p = s * 4 + wave; p < nn; p += SLICES * 4) {
        const int i = p / n;
        const int j = p - i * n;
        if (i >= j) continue;
        const float4* ya = (const float4*)(y + (size_t)slist[i] * D) + lane * 2;
        const float4* yb = (const float4*)(y + (size_t)slist[j] * D) + lane * 2;
        const float4 u0 = ya[0], u1 = ya[1];
        const float4 v0 = yb[0], v1 = yb[1];
        float d, ssd = 0.f;
        d = u0.x - v0.x; ssd += d * d;
        d = u0.y - v0.y; ssd += d * d;
        d = u0.z - v0.z; ssd += d * d;
        d = u0.w - v0.w; ssd += d * d;
        d = u1.x - v1.x; ssd += d * d;
        d = u1.y - v1.y; ssd += d * d;
        d = u1.z - v1.z; ssd += d * d;
        d = u1.w - v1.w; ssd += d * d;
        for (int off = 32; off > 0; off >>= 1) ssd += __shfl_xor(ssd, off, 64);
        const float dd = sqrtf(ssd);
        if (dd > t0) { t1 = t0; t0 = dd; }
        else if (dd > t1) { t1 = dd; }
    }

    __shared__ float s0[4], s1[4];
    if (lane == 0) { s0[wave] = t0; s1[wave] = t1; }
    __syncthreads();
    if (t == 0) {
        float b0 = -INFINITY, b1 = -INFINITY;
        for (int w = 0; w < 4; ++w) {
            const float a0 = s0[w], a1 = s1[w];
            if (a0 > b0) { b1 = b0; b0 = a0; } else if (a0 > b1) { b1 = a0; }
            if (a1 > b0) { b1 = b0; b0 = a1; } else if (a1 > b1) { b1 = a1; }
        }
        blk_top[(c * SLICES + s) * 2]     = b0;
        blk_top[(c * SLICES + s) * 2 + 1] = b1;
    }
}

// 1 block x 1024 threads (16 waves):
//  A) wave w merges slice-partials of classes 2w and 2w+1 (64 vals = 64 lanes)
//  B) waves stride the 1024 center-pair slots (lane-split-D distance, wave min)
//  C) thread 0 combines.
__global__ void final_kernel(const float* __restrict__ centers,
                             const float* __restrict__ blk_top,
                             float* __restrict__ out) {
    const int t = threadIdx.x;
    const int wave = t >> 6;
    const int lane = t & 63;
    __shared__ float li_sh[NC];
    __shared__ float mn_sh[16];

    // A) top-2 merge per class (butterfly top-2)
    for (int cc = 0; cc < 2; ++cc) {
        const int c = wave * 2 + cc;
        float t0 = blk_top[c * SLICES * 2 + lane];
        float t1 = -INFINITY;
        for (int off = 32; off > 0; off >>= 1) {
            const float o0 = __shfl_xor(t0, off, 64);
            const float o1 = __shfl_xor(t1, off, 64);
            if (o0 > t0) { t1 = fmaxf(t0, o1); t0 = o0; }
            else         { t1 = fmaxf(t1, o0); }
        }
        if (lane == 0) li_sh[c] = 2.0f / (t0 + t1);
    }

    // B) min distance over distinct center pairs
    float dmin = INFINITY;
    for (int slot = wave; slot < NC * NC; slot += 16) {
        const int i = slot >> 5;
        const int j = slot & 31;
        if (i >= j) continue;
        const float4* ca = (const float4*)(centers + i * D) + lane * 2;
        const float4* cb = (const float4*)(centers + j * D) + lane * 2;
        const float4 u0 = ca[0], u1 = ca[1];
        const float4 v0 = cb[0], v1 = cb[1];
        float d, ssd = 0.f;
        d = u0.x - v0.x; ssd += d * d;
        d = u0.y - v0.y; ssd += d * d;
        d = u0.z - v0.z; ssd += d * d;
        d = u0.w - v0.w; ssd += d * d;
        d = u1.x - v1.x; ssd += d * d;
        d = u1.y - v1.y; ssd += d * d;
        d = u1.z - v1.z; ssd += d * d;
        d = u1.w - v1.w; ssd += d * d;
        for (int off = 32; off > 0; off >>= 1) ssd += __shfl_xor(ssd, off, 64);
        dmin = fminf(dmin, sqrtf(ssd));
    }
    if (lane == 0) mn_sh[wave] = dmin;
    __syncthreads();

    // C) combine
    if (t == 0) {
        float m = INFINITY;
        for (int w = 0; w < 16; ++w) m = fminf(m, mn_sh[w]);
        float li = 0.f;
        for (int c = 0; c < NC; ++c) li += li_sh[c];
        out[0] = 1.0f * li + 0.5f * fmaxf(10.0f - m, 0.0f);
    }
}

extern "C" void kernel_launch(void* const* d_in, const int* in_sizes, int n_in,
                              void* d_out, int out_size, void* d_ws, size_t ws_size,
                              hipStream_t stream) {
    const float* y      = (const float*)d_in[0];
    const int*   target = (const int*)d_in[1];
    float*       out    = (float*)d_out;

    float* centers = (float*)d_ws;
    float* blk_top = centers + NC * D;

    fused_main_kernel<<<dim3(NC, SLICES + 1), 256, 0, stream>>>(y, target, centers, blk_top);
    final_kernel<<<1, 1024, 0, stream>>>(centers, blk_top, out);
}